// Round 3
// baseline (1272.792 us; speedup 1.0000x reference)
//
#include <hip/hip_runtime.h>
#include <cstddef>

#define D 1024
#define H 16
#define S 2048
#define B 2
#define M_ROWS (B * S)   // 4096
#define NT 16            // 128-col score tiles per row
#define NEG_BIG_F (-1.0e9f)
#define PADK 72          // 64 + 8 shorts: 144-B rows (16-B aligned), conflict-light

// bf16x3 fp32-emulation on MFMA:  x = hi + lo (bf16 RN each);
// a*b ~= ah*bh + ah*bl + al*bh  (drop al*bl ~ 2^-18 |ab|), fp32 accumulate.
typedef short bfrag __attribute__((ext_vector_type(8)));   // 8 bf16 = 4 VGPR
typedef float f32x4 __attribute__((ext_vector_type(4)));

__device__ __forceinline__ unsigned short bf_rn(float x) {
    unsigned u = __float_as_uint(x);
    u += 0x7FFFu + ((u >> 16) & 1u);      // round-to-nearest-even
    return (unsigned short)(u >> 16);
}
__device__ __forceinline__ float bf2f(unsigned short h) {
    return __uint_as_float(((unsigned)h) << 16);
}

__device__ __forceinline__ void load16(const float4* __restrict__ g, float (&x)[16]) {
#pragma unroll
    for (int q = 0; q < 4; q++) {
        float4 t = g[q];
        x[q*4+0] = t.x; x[q*4+1] = t.y; x[q*4+2] = t.z; x[q*4+3] = t.w;
    }
}

__device__ __forceinline__ void split16_store(const float (&x)[16],
                                              short* __restrict__ hp,
                                              short* __restrict__ lp) {
    __align__(16) short hs[16], ls[16];
#pragma unroll
    for (int e = 0; e < 16; e++) {
        unsigned short hh = bf_rn(x[e]);
        hs[e] = (short)hh;
        ls[e] = (short)bf_rn(x[e] - bf2f(hh));
    }
    *(bfrag*)(hp)     = *(const bfrag*)&hs[0];
    *(bfrag*)(hp + 8) = *(const bfrag*)&hs[8];
    *(bfrag*)(lp)     = *(const bfrag*)&ls[0];
    *(bfrag*)(lp + 8) = *(const bfrag*)&ls[8];
}

// copy 16 bf16 (32 B) global -> LDS
__device__ __forceinline__ void copy16(const unsigned short* __restrict__ g,
                                       short* __restrict__ l) {
    *(bfrag*)l       = *(const bfrag*)g;
    *(bfrag*)(l + 8) = *(const bfrag*)(g + 8);
}

#define MFMA3(accv, AH, AL, BH, BL)                                          \
    accv = __builtin_amdgcn_mfma_f32_16x16x32_bf16(AH, BH, accv, 0, 0, 0);   \
    accv = __builtin_amdgcn_mfma_f32_16x16x32_bf16(AH, BL, accv, 0, 0, 0);   \
    accv = __builtin_amdgcn_mfma_f32_16x16x32_bf16(AL, BH, accv, 0, 0, 0);

// ---------------------------------------------------------------------------
// W [K][N] fp32 -> WTh/WTl [N][K] bf16 hi/lo (transpose + split, once)
// ---------------------------------------------------------------------------
__global__ __launch_bounds__(256) void transpose_split_w(
    const float* __restrict__ Win, unsigned short* __restrict__ WTh,
    unsigned short* __restrict__ WTl)
{
    __shared__ float t[64][65];
    const int tid = threadIdx.x;
    const int bx = blockIdx.x * 64, by = blockIdx.y * 64;
    const int c = tid & 63, r0 = tid >> 6;
#pragma unroll
    for (int r = r0; r < 64; r += 4)
        t[r][c] = Win[(size_t)(by + r) * D + bx + c];
    __syncthreads();
#pragma unroll
    for (int r = r0; r < 64; r += 4) {
        float x = t[c][r];
        unsigned short hh = bf_rn(x);
        unsigned short ll = bf_rn(x - bf2f(hh));
        WTh[(size_t)(bx + r) * D + by + c] = hh;
        WTl[(size_t)(bx + r) * D + by + c] = ll;
    }
}

// ---------------------------------------------------------------------------
// C = A @ W + bias via bf16x3 MFMA.  W pre-split [N][K] bf16.
// A either fp32 [M][1024] (Af != null, split on stage) or pre-split bf16
// (Ah_g/Al_g).  mode 0: fp32 row-major out (Cf).
// mode 1: split out [B,H,S,64] (Ch/Cl).  mode 2: split V^T out [B,H,64,S].
// Tile 128x64, BK=64, 4 waves (2x2), wave = 64x32 (4x2 frags).
// ---------------------------------------------------------------------------
__global__ __launch_bounds__(256) void mm_proj(
    const float* __restrict__ Af,
    const unsigned short* __restrict__ Ah_g, const unsigned short* __restrict__ Al_g,
    const unsigned short* __restrict__ WTh, const unsigned short* __restrict__ WTl,
    const float* __restrict__ bias, float* __restrict__ Cf,
    unsigned short* __restrict__ Ch, unsigned short* __restrict__ Cl, int mode)
{
    __shared__ __align__(16) short Ah[128][PADK], Al[128][PADK];
    __shared__ __align__(16) short Bh[64][PADK],  Bl[64][PADK];

    const int tid  = threadIdx.x;
    const int lane = tid & 63, wid = tid >> 6;
    const int wm = (wid >> 1) * 64, wn = (wid & 1) * 32;
    const int lr = lane >> 4, lc = lane & 15;
    const int tile_n = blockIdx.x * 64;
    const int tile_m = blockIdx.y * 128;

    f32x4 acc[4][2] = {};

    for (int k0 = 0; k0 < D; k0 += 64) {
        __syncthreads();
        if (Af) {
            // A fp32 128x64: 512 16-float segs, 2/thread, split on stage
#pragma unroll
            for (int p = 0; p < 2; p++) {
                int s = tid + p * 256;
                int row = s >> 2, kseg = (s & 3) * 16;
                float x[16];
                load16((const float4*)&Af[(size_t)(tile_m + row) * D + k0 + kseg], x);
                split16_store(x, &Ah[row][kseg], &Al[row][kseg]);
            }
        } else {
            // A pre-split: pure copy, 64 shorts per array per thread
            int row = tid >> 1, off = (tid & 1) * 32;
            const size_t ga = (size_t)(tile_m + row) * D + k0;
            copy16(&Ah_g[ga + off],      &Ah[row][off]);
            copy16(&Ah_g[ga + off + 16], &Ah[row][off + 16]);
            copy16(&Al_g[ga + off],      &Al[row][off]);
            copy16(&Al_g[ga + off + 16], &Al[row][off + 16]);
        }
        {
            // W pre-split 64x64: copy
            int row = tid >> 2, seg = (tid & 3) * 16;
            const size_t gw = (size_t)(tile_n + row) * D + k0 + seg;
            copy16(&WTh[gw], &Bh[row][seg]);
            copy16(&WTl[gw], &Bl[row][seg]);
        }
        __syncthreads();
#pragma unroll
        for (int ks = 0; ks < 2; ks++) {
            const int ko = ks * 32 + lr * 8;
            bfrag ah[4], al[4], bh[2], bl[2];
#pragma unroll
            for (int fm = 0; fm < 4; fm++) {
                ah[fm] = *(const bfrag*)&Ah[wm + fm * 16 + lc][ko];
                al[fm] = *(const bfrag*)&Al[wm + fm * 16 + lc][ko];
            }
#pragma unroll
            for (int fn = 0; fn < 2; fn++) {
                bh[fn] = *(const bfrag*)&Bh[wn + fn * 16 + lc][ko];
                bl[fn] = *(const bfrag*)&Bl[wn + fn * 16 + lc][ko];
            }
#pragma unroll
            for (int fm = 0; fm < 4; fm++)
#pragma unroll
                for (int fn = 0; fn < 2; fn++) {
                    MFMA3(acc[fm][fn], ah[fm], al[fm], bh[fn], bl[fn])
                }
        }
    }

    // epilogue; C frag layout: col = lane&15, row = (lane>>4)*4 + reg
#pragma unroll
    for (int fm = 0; fm < 4; fm++)
#pragma unroll
        for (int fn = 0; fn < 2; fn++) {
            const int gm0 = tile_m + wm + fm * 16 + lr * 4;
            const int gn  = tile_n + wn + fn * 16 + lc;
            const float bv = bias[gn];
#pragma unroll
            for (int r = 0; r < 4; r++) {
                int gm = gm0 + r;
                float val = acc[fm][fn][r] + bv;
                if (mode == 0) {
                    Cf[(size_t)gm * D + gn] = val;
                } else {
                    unsigned short hh = bf_rn(val);
                    unsigned short ll = bf_rn(val - bf2f(hh));
                    int bb = gm >> 11, ss = gm & (S - 1);
                    int hd = gn >> 6,  dd = gn & 63;
                    size_t a = (mode == 1)
                        ? ((((size_t)(bb * H + hd) * S + ss) << 6) + dd)
                        : ((((size_t)(bb * H + hd) << 6) + dd) * S + ss);
                    Ch[a] = hh; Cl[a] = ll;
                }
            }
        }
}

// ---------------------------------------------------------------------------
// scores: Sc = 0.125 * Q K^T with mask semantics; raw masked scores written;
// per-(row, 128-col tile) softmax partials to aux.  Q/K pre-split bf16.
// Tile 128x128, K=64 single stage.  4 waves (2x2), wave = 64x64 (4x4 frags).
// ---------------------------------------------------------------------------
__global__ __launch_bounds__(256) void scores_mm(
    const unsigned short* __restrict__ Qh_g, const unsigned short* __restrict__ Ql_g,
    const unsigned short* __restrict__ Kh_g, const unsigned short* __restrict__ Kl_g,
    const float* __restrict__ mask, float* __restrict__ Sc,
    float2* __restrict__ aux)
{
    __shared__ __align__(16) short Qh[128][PADK], Ql[128][PADK];
    __shared__ __align__(16) short Kh[128][PADK], Kl[128][PADK];
    __shared__ float smx[2][128], sls[2][128];

    const int tid  = threadIdx.x;
    const int lane = tid & 63, wid = tid >> 6;
    const int wm = (wid >> 1) * 64, wn = (wid & 1) * 64;
    const int lr = lane >> 4, lc = lane & 15;
    const int bh = blockIdx.z, b = bh >> 4;
    const int tile_m = blockIdx.y * 128, tile_n = blockIdx.x * 128;

    // staging: pure copies of pre-split tiles (row = tid>>1, 32-short halves)
    {
        const int row = tid >> 1, off = (tid & 1) * 32;
        const size_t gq = (((size_t)bh * S + tile_m + row) << 6);
        const size_t gk = (((size_t)bh * S + tile_n + row) << 6);
        copy16(&Qh_g[gq + off],      &Qh[row][off]);
        copy16(&Qh_g[gq + off + 16], &Qh[row][off + 16]);
        copy16(&Ql_g[gq + off],      &Ql[row][off]);
        copy16(&Ql_g[gq + off + 16], &Ql[row][off + 16]);
        copy16(&Kh_g[gk + off],      &Kh[row][off]);
        copy16(&Kh_g[gk + off + 16], &Kh[row][off + 16]);
        copy16(&Kl_g[gk + off],      &Kl[row][off]);
        copy16(&Kl_g[gk + off + 16], &Kl[row][off + 16]);
    }
    __syncthreads();

    f32x4 acc[4][4] = {};
#pragma unroll
    for (int ks = 0; ks < 2; ks++) {
        const int ko = ks * 32 + lr * 8;
        bfrag qh[4], ql[4], kh[4], kl[4];
#pragma unroll
        for (int fm = 0; fm < 4; fm++) {
            qh[fm] = *(const bfrag*)&Qh[wm + fm * 16 + lc][ko];
            ql[fm] = *(const bfrag*)&Ql[wm + fm * 16 + lc][ko];
        }
#pragma unroll
        for (int fn = 0; fn < 4; fn++) {
            kh[fn] = *(const bfrag*)&Kh[wn + fn * 16 + lc][ko];
            kl[fn] = *(const bfrag*)&Kl[wn + fn * 16 + lc][ko];
        }
#pragma unroll
        for (int fm = 0; fm < 4; fm++)
#pragma unroll
            for (int fn = 0; fn < 4; fn++) {
                MFMA3(acc[fm][fn], qh[fm], ql[fm], kh[fn], kl[fn])
            }
    }

    const float* mb = mask + (size_t)b * S * S;
    float* Sh = Sc + (size_t)bh * S * S;
#pragma unroll
    for (int fm = 0; fm < 4; fm++)
#pragma unroll
        for (int r = 0; r < 4; r++) {
            const int lrow = wm + fm * 16 + lr * 4 + r;
            const int gm = tile_m + lrow;
            float sc[4];
#pragma unroll
            for (int fn = 0; fn < 4; fn++) {
                const int gn = tile_n + wn + fn * 16 + lc;
                float v = acc[fm][fn][r] * 0.125f;
                v *= mb[(size_t)gm * S + gn];
                if (v == 0.0f) v = NEG_BIG_F;
                sc[fn] = v;
                Sh[(size_t)gm * S + gn] = v;
            }
            float mx = fmaxf(fmaxf(sc[0], sc[1]), fmaxf(sc[2], sc[3]));
#pragma unroll
            for (int d2 = 1; d2 < 16; d2 <<= 1) mx = fmaxf(mx, __shfl_xor(mx, d2));
            float ls = __expf(sc[0] - mx) + __expf(sc[1] - mx) +
                       __expf(sc[2] - mx) + __expf(sc[3] - mx);
#pragma unroll
            for (int d2 = 1; d2 < 16; d2 <<= 1) ls += __shfl_xor(ls, d2);
            if (lc == 0) { smx[wn >> 6][lrow] = mx; sls[wn >> 6][lrow] = ls; }
        }
    __syncthreads();
    if (tid < 128) {
        float m0 = smx[0][tid], m1 = smx[1][tid];
        float mx = fmaxf(m0, m1);
        float ls = sls[0][tid] * __expf(m0 - mx) + sls[1][tid] * __expf(m1 - mx);
        aux[((size_t)bh * S + tile_m + tid) * NT + blockIdx.x] = make_float2(mx, ls);
    }
}

// ---------------------------------------------------------------------------
__global__ __launch_bounds__(256) void reduce_stats(
    const float2* __restrict__ aux, float2* __restrict__ stats)
{
    const int row = blockIdx.x * 256 + threadIdx.x;   // < B*H*S
    const float2* a = aux + (size_t)row * NT;
    float m = -3.0e38f;
#pragma unroll
    for (int t = 0; t < NT; t++) m = fmaxf(m, a[t].x);
    float l = 0.0f;
#pragma unroll
    for (int t = 0; t < NT; t++) l += a[t].y * __expf(a[t].x - m);
    stats[row] = make_float2(m, 1.0f / l);
}

// ---------------------------------------------------------------------------
// pv: normalize raw scores on the fly (p = exp(s-m)*inv), write alignment
// back in place, Ctx = P @ V via bf16x3 MFMA with pre-split V^T [bh][64][S].
// Writes Ctx pre-split bf16 [4096][1024] for the output projection.
// Tile 64x64, BK=64, 4 waves (2x2), wave = 32x32 (2x2 frags).
// ---------------------------------------------------------------------------
__global__ __launch_bounds__(256) void pv_mm(
    float* __restrict__ P,
    const unsigned short* __restrict__ VTh_g, const unsigned short* __restrict__ VTl_g,
    const float2* __restrict__ stats,
    unsigned short* __restrict__ Ctxh, unsigned short* __restrict__ Ctxl)
{
    __shared__ __align__(16) short Ph[64][PADK], Pl[64][PADK];
    __shared__ __align__(16) short Vh[64][PADK], Vl[64][PADK];
    __shared__ float2 st[64];

    const int tid  = threadIdx.x;
    const int lane = tid & 63, wid = tid >> 6;
    const int wm = (wid >> 1) * 32, wn = (wid & 1) * 32;
    const int lr = lane >> 4, lc = lane & 15;
    const int tile_m = blockIdx.x * 64;
    const int bh = blockIdx.y, b = bh >> 4, h = bh & 15;

    float* Pg = P + (size_t)bh * S * S;
    const size_t vbase = ((size_t)bh << 6) * S;

    if (tid < 64) st[tid] = stats[(size_t)bh * S + tile_m + tid];
    __syncthreads();

    const int prow = tid >> 2, pseg = (tid & 3) * 16;
    const float2 ms = st[prow];

    f32x4 acc[2][2] = {};

    for (int k0 = 0; k0 < S; k0 += 64) {
        // P tile 64x64: load raw, normalize, write back, split into LDS
        {
            float4* gp = (float4*)&Pg[(size_t)(tile_m + prow) * S + k0 + pseg];
            float x[16];
#pragma unroll
            for (int q = 0; q < 4; q++) {
                float4 t = gp[q];
                t.x = __expf(t.x - ms.x) * ms.y;
                t.y = __expf(t.y - ms.x) * ms.y;
                t.z = __expf(t.z - ms.x) * ms.y;
                t.w = __expf(t.w - ms.x) * ms.y;
                gp[q] = t;
                x[q*4+0] = t.x; x[q*4+1] = t.y; x[q*4+2] = t.z; x[q*4+3] = t.w;
            }
            split16_store(x, &Ph[prow][pseg], &Pl[prow][pseg]);
        }
        // V^T tile 64(d) x 64(k): pure copy of pre-split
        {
            const size_t gv = vbase + (size_t)prow * S + k0 + pseg;
            copy16(&VTh_g[gv], &Vh[prow][pseg]);
            copy16(&VTl_g[gv], &Vl[prow][pseg]);
        }
        __syncthreads();
#pragma unroll
        for (int ks = 0; ks < 2; ks++) {
            const int ko = ks * 32 + lr * 8;
            bfrag ah[2], al[2], bh2[2], bl2[2];
#pragma unroll
            for (int fm = 0; fm < 2; fm++) {
                ah[fm] = *(const bfrag*)&Ph[wm + fm * 16 + lc][ko];
                al[fm] = *(const bfrag*)&Pl[wm + fm * 16 + lc][ko];
            }
#pragma unroll
            for (int fn = 0; fn < 2; fn++) {
                bh2[fn] = *(const bfrag*)&Vh[wn + fn * 16 + lc][ko];
                bl2[fn] = *(const bfrag*)&Vl[wn + fn * 16 + lc][ko];
            }
#pragma unroll
            for (int fm = 0; fm < 2; fm++)
#pragma unroll
                for (int fn = 0; fn < 2; fn++) {
                    MFMA3(acc[fm][fn], ah[fm], al[fm], bh2[fn], bl2[fn])
                }
        }
        __syncthreads();
    }

#pragma unroll
    for (int fm = 0; fm < 2; fm++)
#pragma unroll
        for (int fn = 0; fn < 2; fn++)
#pragma unroll
            for (int r = 0; r < 4; r++) {
                int s_ = tile_m + wm + fm * 16 + lr * 4 + r;
                int dcol = (h << 6) + wn + fn * 16 + lc;
                float val = acc[fm][fn][r];
                unsigned short hh = bf_rn(val);
                unsigned short ll = bf_rn(val - bf2f(hh));
                size_t a = ((size_t)b * S + s_) * D + dcol;
                Ctxh[a] = hh; Ctxl[a] = ll;
            }
}

// ---------------------------------------------------------------------------
extern "C" void kernel_launch(void* const* d_in, const int* in_sizes, int n_in,
                              void* d_out, int out_size, void* d_ws, size_t ws_size,
                              hipStream_t stream)
{
    const float* q    = (const float*)d_in[0];
    const float* v    = (const float*)d_in[1];
    const float* mask = (const float*)d_in[2];
    const float* wq_w = (const float*)d_in[3];
    const float* wq_b = (const float*)d_in[4];
    const float* wk_w = (const float*)d_in[5];
    const float* wk_b = (const float*)d_in[6];
    const float* wv_w = (const float*)d_in[7];
    const float* wv_b = (const float*)d_in[8];
    const float* wo_w = (const float*)d_in[9];
    const float* wo_b = (const float*)d_in[10];

    float* out_heads = (float*)d_out;                       // [B,S,D]
    float* out_align = (float*)d_out + (size_t)B * S * D;   // [B,H,S,S]

    // ws layout (ushorts / bytes), total 67.2 MB (proven footprint):
    //  [ 0.0 MB) Qh/Ql  [B,H,S,64] bf16 x2      (16.8 MB)  -> Ctxh/Ctxl overlay
    //  [16.8 MB) Kh/Kl                           (16.8 MB)
    //  [33.6 MB) VTh/VTl [B,H,64,S]              (16.8 MB)
    //  [50.3 MB) W splits: (wq,wk,wv,wo) x (h,l) (16.8 MB)
    // aux (8.4 MB) + stats (0.5 MB) live in d_out's heads region (16.8 MB),
    // which is dead until the final projection overwrites it entirely.
    const size_t qkv = (size_t)B * H * S * 64;              // 4,194,304 elems
    const size_t wsz = (size_t)D * D;                       // 1,048,576 elems
    unsigned short* wsu = (unsigned short*)d_ws;
    unsigned short* Qh  = wsu;
    unsigned short* Ql  = Qh + qkv;
    unsigned short* Kh  = Ql + qkv;
    unsigned short* Kl  = Kh + qkv;
    unsigned short* VTh = Kl + qkv;
    unsigned short* VTl = VTh + qkv;
    unsigned short* Wq_h = VTl + qkv;
    unsigned short* Wq_l = Wq_h + wsz;
    unsigned short* Wk_h = Wq_l + wsz;
    unsigned short* Wk_l = Wk_h + wsz;
    unsigned short* Wv_h = Wk_l + wsz;
    unsigned short* Wv_l = Wv_h + wsz;
    unsigned short* Wo_h = Wv_l + wsz;
    unsigned short* Wo_l = Wo_h + wsz;
    unsigned short* Ctxh = Qh;            // overlay: Q dead after scores
    unsigned short* Ctxl = Ql;

    float2* aux   = (float2*)out_heads;                     // 8.4 MB
    float2* stats = (float2*)(out_heads + (size_t)2 * 1024 * 1024 + 131072);

    dim3 tg(16, 16);
    transpose_split_w<<<tg, 256, 0, stream>>>(wq_w, Wq_h, Wq_l);
    transpose_split_w<<<tg, 256, 0, stream>>>(wk_w, Wk_h, Wk_l);
    transpose_split_w<<<tg, 256, 0, stream>>>(wv_w, Wv_h, Wv_l);
    transpose_split_w<<<tg, 256, 0, stream>>>(wo_w, Wo_h, Wo_l);

    dim3 pg(D / 64, M_ROWS / 128);        // (16, 32)
    mm_proj<<<pg, 256, 0, stream>>>(q, nullptr, nullptr, Wq_h, Wq_l, wq_b,
                                    nullptr, Qh, Ql, 1);
    mm_proj<<<pg, 256, 0, stream>>>(v, nullptr, nullptr, Wk_h, Wk_l, wk_b,
                                    nullptr, Kh, Kl, 1);
    mm_proj<<<pg, 256, 0, stream>>>(v, nullptr, nullptr, Wv_h, Wv_l, wv_b,
                                    nullptr, VTh, VTl, 2);

    dim3 sg(S / 128, S / 128, B * H);     // (16, 16, 32)
    scores_mm<<<sg, 256, 0, stream>>>(Qh, Ql, Kh, Kl, mask, out_align, aux);

    reduce_stats<<<dim3((B * H * S) / 256), 256, 0, stream>>>(aux, stats);

    dim3 vg(S / 64, B * H);               // (32, 32)
    pv_mm<<<vg, 256, 0, stream>>>(out_align, VTh, VTl, stats, Ctxh, Ctxl);

    mm_proj<<<pg, 256, 0, stream>>>(nullptr, Ctxh, Ctxl, Wo_h, Wo_l, wo_b,
                                    out_heads, nullptr, nullptr, 0);
}